// Round 6
// baseline (266.242 us; speedup 1.0000x reference)
//
#include <hip/hip_runtime.h>

typedef __bf16 bf16x8 __attribute__((ext_vector_type(8)));
typedef float f32x4 __attribute__((ext_vector_type(4)));
typedef float f32x16 __attribute__((ext_vector_type(16)));

#define MFMA16(a, b, c) __builtin_amdgcn_mfma_f32_16x16x32_bf16(a, b, c, 0, 0, 0)
#define MFMA32(a, b, c) __builtin_amdgcn_mfma_f32_32x32x16_bf16(a, b, c, 0, 0, 0)
#define GLDS16(g, l)                                                              \
  __builtin_amdgcn_global_load_lds((const __attribute__((address_space(1))) void*)(g), \
                                   (__attribute__((address_space(3))) void*)(l), 16, 0, 0)

static __device__ __forceinline__ unsigned pack_bf16(float a, float b) {
  union { __bf16 h[2]; unsigned u; } t;
  t.h[0] = (__bf16)a; t.h[1] = (__bf16)b;
  return t.u;
}

// ---------------- convert f32 -> bf16 (straight) ----------------
__global__ __launch_bounds__(256) void cvt_bf16_kernel(const float* __restrict__ in,
                                                       __bf16* __restrict__ out, int n4) {
  int i = blockIdx.x * 256 + threadIdx.x;
  if (i < n4) {
    float4 v = ((const float4*)in)[i];
    union { __bf16 b[4]; uint2 u; } t;
    t.b[0] = (__bf16)v.x; t.b[1] = (__bf16)v.y;
    t.b[2] = (__bf16)v.z; t.b[3] = (__bf16)v.w;
    ((uint2*)out)[i] = t.u;
  }
}

// ---------------- transpose-convert both weights in one launch ----------------
__global__ __launch_bounds__(256) void transpose_w_kernel(const float* __restrict__ Wq,
                                                          __bf16* __restrict__ WqT,
                                                          const float* __restrict__ Wo,
                                                          __bf16* __restrict__ WoT) {
  const int Kd = 1024;
  int bx = blockIdx.x;
  const float* W; __bf16* WT; int Nd, n0;
  if (bx < 96) { W = Wq; WT = WqT; Nd = 3072; n0 = bx * 32; }
  else         { W = Wo; WT = WoT; Nd = 1024; n0 = (bx - 96) * 32; }
  __shared__ float tile[32][33];
  int k0 = blockIdx.y * 32;
  int tid = threadIdx.x;
  int kk = tid >> 3, nn = (tid & 7) * 4;
  float4 v = *(const float4*)&W[(size_t)(k0 + kk) * Nd + n0 + nn];
  tile[kk][nn] = v.x; tile[kk][nn + 1] = v.y;
  tile[kk][nn + 2] = v.z; tile[kk][nn + 3] = v.w;
  __syncthreads();
  int n2 = tid >> 3, k2 = (tid & 7) * 4;
  union { __bf16 b[4]; uint2 u; } t;
  t.b[0] = (__bf16)tile[k2][n2];
  t.b[1] = (__bf16)tile[k2 + 1][n2];
  t.b[2] = (__bf16)tile[k2 + 2][n2];
  t.b[3] = (__bf16)tile[k2 + 3][n2];
  *(uint2*)&WT[(size_t)(n0 + n2) * Kd + k0 + k2] = t.u;
}

// ---------------- GEMM: C[M,N] = A[M,1024] @ BT[N,1024]^T + bias ----------------
template <bool OUT_F32, int NT>
__global__ __launch_bounds__(256) void gemm_kernel(const __bf16* __restrict__ A,
                                                   const __bf16* __restrict__ BT,
                                                   const float* __restrict__ bias,
                                                   void* __restrict__ Cout, int N,
                                                   int qn, float qs) {
  const int K = 1024;
  const int NJ = NT / 32;
  __shared__ __align__(16) __bf16 As[2][128 * 32];
  __shared__ __align__(16) __bf16 Bs[2][NT * 32];
  int tid = threadIdx.x;
  int wave = tid >> 6, lane = tid & 63;
  int quad = lane >> 4, l16 = lane & 15;
  int m0 = blockIdx.x * 128, n0 = blockIdx.y * NT;
  int wm = (wave >> 1) * 64, wn = (wave & 1) * (NT / 2);

  int srow = tid >> 2, scol = (tid & 3) * 8;
  const __bf16* aptr = A + (size_t)(m0 + srow) * K + scol;
  const __bf16* bptr = BT + (size_t)(n0 + srow) * K + scol;

  f32x4 acc[4][NJ] = {};
  for (int k0 = 0; k0 < K; k0 += 64) {
#pragma unroll
    for (int kh = 0; kh < 2; kh++) {
      GLDS16(aptr + k0 + kh * 32, &As[kh][wave * 512]);
      GLDS16(aptr + (size_t)64 * K + k0 + kh * 32, &As[kh][wave * 512 + 2048]);
      GLDS16(bptr + k0 + kh * 32, &Bs[kh][wave * 512]);
      if (NT == 128) GLDS16(bptr + (size_t)64 * K + k0 + kh * 32, &Bs[kh][wave * 512 + 2048]);
    }
    __syncthreads();
#pragma unroll
    for (int kh = 0; kh < 2; kh++) {
      bf16x8 af[4], bf[NJ];
      for (int i = 0; i < 4; i++)
        af[i] = *(bf16x8*)&As[kh][(wm + i * 16 + l16) * 32 + quad * 8];
      for (int j = 0; j < NJ; j++)
        bf[j] = *(bf16x8*)&Bs[kh][(wn + j * 16 + l16) * 32 + quad * 8];
      for (int i = 0; i < 4; i++)
        for (int j = 0; j < NJ; j++)
          acc[i][j] = MFMA16(af[i], bf[j], acc[i][j]);
    }
    __syncthreads();
  }
  for (int j = 0; j < NJ; j++) {
    int col = n0 + wn + j * 16 + l16;
    float bv = bias[col];
    float sc = (col < qn) ? qs : 1.0f;
    for (int i = 0; i < 4; i++) {
      int rowb = m0 + wm + i * 16 + quad * 4;
      for (int r = 0; r < 4; r++) {
        float v = (acc[i][j][r] + bv) * sc;
        if (OUT_F32)
          ((float*)Cout)[(size_t)(rowb + r) * N + col] = v;
        else
          ((__bf16*)Cout)[(size_t)(rowb + r) * N + col] = (__bf16)v;
      }
    }
  }
}

// ---------------- transpose V slice of qkv -> Vt [b][h][d][t] ----------------
__global__ __launch_bounds__(256) void transpose_v_kernel(const __bf16* __restrict__ qkv,
                                                          __bf16* __restrict__ Vt) {
  const int T = 2048, C3 = 3072;
  __shared__ __align__(16) __bf16 tile[64][72];
  int t0 = blockIdx.x * 64;
  int h = blockIdx.y, b = blockIdx.z;
  int tid = threadIdx.x;
  int tt = tid >> 2, c = (tid & 3) * 16;
  const __bf16* src = qkv + (size_t)(b * T + t0 + tt) * C3 + 2048 + h * 64 + c;
  *(uint4*)&tile[tt][c] = *(const uint4*)src;
  *(uint4*)&tile[tt][c + 8] = *(const uint4*)(src + 8);
  __syncthreads();
  int dd = tid >> 2, t2 = (tid & 3) * 16;
  union { __bf16 b_[16]; uint4 u[2]; } o;
  for (int i = 0; i < 16; i++) o.b_[i] = tile[t2 + i][dd];
  __bf16* dst = Vt + ((size_t)(b * 16 + h) * 64 + dd) * T + t0 + t2;
  *(uint4*)dst = o.u[0];
  *(uint4*)(dst + 8) = o.u[1];
}

// ---------------- flash attention v6: 1-wave blocks, zero barriers ----------------
// grid 2048 x 64 thr. Each wave owns 32 q-rows; KV tile 32; 64 tiles.
// K (A-frag, m=t) and V (B-frag, n=d) are per-lane row reads -> direct global
// b128 loads, software-pipelined one tile ahead in registers. No LDS staging,
// no __syncthreads. S^T = K.Q^T gives q-in-lane; P round-trips a 2.5 KB LDS
// buffer (b64 packed writes / b128 reads, stride 40 => floor conflicts).
// XCD locality: bh = bid&31 so all q-blocks of one (b,h) share bid%8.
__global__ __launch_bounds__(64) void attn_kernel(const __bf16* __restrict__ qkv,
                                                  const __bf16* __restrict__ Vt,
                                                  __bf16* __restrict__ O) {
  const int T = 2048, C3 = 3072;
  int bid = blockIdx.x;
  int bh = bid & 31;            // b*? -> b = bh>>4, h = bh&15; bid%8 groups (b,h) per XCD
  int q0 = (bid >> 5) * 32;
  int b = bh >> 4, h = bh & 15;
  int lane = threadIdx.x;
  int l31 = lane & 31, hw = lane >> 5;
  int perm = (lane ^ 32) << 2;

  __shared__ __align__(16) __bf16 Ps[32 * 40];  // P[q][t'], stride 40

  // Q as B-operand frags: lane n=q=l31, k=d chunks
  const __bf16* qp = qkv + (size_t)(b * T + q0 + l31) * C3 + h * 64 + hw * 8;
  bf16x8 bq[4];
#pragma unroll
  for (int c = 0; c < 4; c++) bq[c] = *(const bf16x8*)(qp + c * 16);

  // K rows: lane m=t=l31; V rows: lane n=d (per dt half)
  const __bf16* kptr = qkv + (size_t)(b * T + l31) * C3 + 1024 + h * 64 + hw * 8;
  const __bf16* vptr = Vt + ((size_t)bh * 64 + l31) * T + hw * 8;

  f32x16 o0 = {}, o1 = {};
  float ls_acc = 0.f;

  bf16x8 kfA[4], vfA[4], kfB[4], vfB[4];

#define LOAD_TILE(t0, kf, vf)                                                     \
  {                                                                               \
    const __bf16* kp_ = kptr + (size_t)(t0)*C3;                                   \
    kf[0] = *(const bf16x8*)(kp_);                                                \
    kf[1] = *(const bf16x8*)(kp_ + 16);                                           \
    kf[2] = *(const bf16x8*)(kp_ + 32);                                           \
    kf[3] = *(const bf16x8*)(kp_ + 48);                                           \
    const __bf16* vp_ = vptr + (t0);                                              \
    vf[0] = *(const bf16x8*)(vp_);                 /* kc0 dt0 */                  \
    vf[1] = *(const bf16x8*)(vp_ + (size_t)32 * T);/* kc0 dt1 */                  \
    vf[2] = *(const bf16x8*)(vp_ + 16);            /* kc1 dt0 */                  \
    vf[3] = *(const bf16x8*)(vp_ + (size_t)32 * T + 16); /* kc1 dt1 */            \
  }

#define COMPUTE_TILE(kf, vf)                                                      \
  {                                                                               \
    f32x16 ss = {};                                                               \
    ss = MFMA32(kf[0], bq[0], ss);                                                \
    ss = MFMA32(kf[1], bq[1], ss);                                                \
    ss = MFMA32(kf[2], bq[2], ss);                                                \
    ss = MFMA32(kf[3], bq[3], ss);                                                \
    _Pragma("unroll") for (int g = 0; g < 4; g++) {                               \
      float e0 = __builtin_amdgcn_exp2f(ss[4 * g + 0]);                           \
      float e1 = __builtin_amdgcn_exp2f(ss[4 * g + 1]);                           \
      float e2 = __builtin_amdgcn_exp2f(ss[4 * g + 2]);                           \
      float e3 = __builtin_amdgcn_exp2f(ss[4 * g + 3]);                           \
      ls_acc += (e0 + e1) + (e2 + e3);                                            \
      uint2 w_;                                                                   \
      w_.x = pack_bf16(e0, e1);                                                   \
      w_.y = pack_bf16(e2, e3);                                                   \
      *(uint2*)&Ps[l31 * 40 + g * 8 + hw * 4] = w_;                               \
    }                                                                             \
    bf16x8 ap0 = *(const bf16x8*)&Ps[l31 * 40 + hw * 8];                          \
    bf16x8 ap1 = *(const bf16x8*)&Ps[l31 * 40 + 16 + hw * 8];                     \
    o0 = MFMA32(ap0, vf[0], o0);                                                  \
    o1 = MFMA32(ap0, vf[1], o1);                                                  \
    o0 = MFMA32(ap1, vf[2], o0);                                                  \
    o1 = MFMA32(ap1, vf[3], o1);                                                  \
  }

  LOAD_TILE(0, kfA, vfA);
  for (int t0 = 0; t0 < T; t0 += 64) {
    LOAD_TILE(t0 + 32, kfB, vfB);
    COMPUTE_TILE(kfA, vfA);
    if (t0 + 64 < T) LOAD_TILE(t0 + 64, kfA, vfA);
    COMPUTE_TILE(kfB, vfB);
  }

  // combine row sums across lane halves (each half holds complementary t's)
  int lsp = __builtin_amdgcn_ds_bpermute(perm, __builtin_bit_cast(int, ls_acc));
  float ls_tot = ls_acc + __builtin_bit_cast(float, lsp);

  // epilogue: O C/D col = d = dt*32 + l31, row = q = (reg&3)+8*(reg>>2)+4*hw
  __bf16* obase = O + (size_t)(b * T + q0) * 1024 + h * 64 + l31;
#pragma unroll
  for (int reg = 0; reg < 16; reg++) {
    int q = (reg & 3) + 8 * (reg >> 2) + 4 * hw;
    float lq = __shfl(ls_tot, q, 64);  // row-q sum lives in lane l31==q
    float inv = 1.0f / lq;
    obase[(size_t)q * 1024] = (__bf16)(o0[reg] * inv);
    obase[(size_t)q * 1024 + 32] = (__bf16)(o1[reg] * inv);
  }
#undef LOAD_TILE
#undef COMPUTE_TILE
}

// ---------------- launch ----------------
extern "C" void kernel_launch(void* const* d_in, const int* in_sizes, int n_in,
                              void* d_out, int out_size, void* d_ws, size_t ws_size,
                              hipStream_t stream) {
  const float* x = (const float*)d_in[0];      // [2,2048,1024]
  const float* W_qkv = (const float*)d_in[1];  // [1024,3072]
  const float* b_qkv = (const float*)d_in[2];  // [3072]
  const float* W_out = (const float*)d_in[3];  // [1024,1024]
  const float* b_out = (const float*)d_in[4];  // [1024]
  float* out = (float*)d_out;                  // [2,2048,1024] f32

  char* ws = (char*)d_ws;
  __bf16* WqkvT = (__bf16*)(ws);               // [3072][1024]  6 MB
  __bf16* WoT = (__bf16*)(ws + 6291456);       // [1024][1024]  2 MB
  __bf16* xb = (__bf16*)(ws + 8388608);        // [4096][1024]  8 MB
  __bf16* qkvb = (__bf16*)(ws + 16777216);     // [4096][3072] 24 MB
  __bf16* Vt = (__bf16*)(ws + 41943040);       // [2][16][64][2048] 8 MB
  __bf16* attnb = xb;  // xb dead after gemm1; reuse for attention output

  const float cs = 0.125f * 1.44269504089f;  // 1/sqrt(64) * log2(e)

  cvt_bf16_kernel<<<4096, 256, 0, stream>>>(x, xb, 1048576);
  transpose_w_kernel<<<dim3(128, 32), 256, 0, stream>>>(W_qkv, WqkvT, W_out, WoT);
  gemm_kernel<false, 128><<<dim3(32, 24), 256, 0, stream>>>(xb, WqkvT, b_qkv, qkvb, 3072,
                                                            1024, cs);
  transpose_v_kernel<<<dim3(32, 16, 2), 256, 0, stream>>>(qkvb, Vt);
  attn_kernel<<<2048, 64, 0, stream>>>(qkvb, Vt, attnb);
  gemm_kernel<true, 64><<<dim3(32, 16), 256, 0, stream>>>(attnb, WoT, b_out, out, 1024,
                                                          0, 1.0f);
}

// Round 7
// 223.228 us; speedup vs baseline: 1.1927x; 1.1927x over previous
//
#include <hip/hip_runtime.h>

typedef __bf16 bf16x8 __attribute__((ext_vector_type(8)));
typedef float f32x2 __attribute__((ext_vector_type(2)));
typedef float f32x4 __attribute__((ext_vector_type(4)));
typedef float f32x16 __attribute__((ext_vector_type(16)));

#define MFMA16(a, b, c) __builtin_amdgcn_mfma_f32_16x16x32_bf16(a, b, c, 0, 0, 0)
#define MFMA32(a, b, c) __builtin_amdgcn_mfma_f32_32x32x16_bf16(a, b, c, 0, 0, 0)
#define GLDS16(g, l)                                                              \
  __builtin_amdgcn_global_load_lds((const __attribute__((address_space(1))) void*)(g), \
                                   (__attribute__((address_space(3))) void*)(l), 16, 0, 0)

static __device__ __forceinline__ unsigned pack_bf16(float a, float b) {
  union { __bf16 h[2]; unsigned u; } t;
  t.h[0] = (__bf16)a; t.h[1] = (__bf16)b;
  return t.u;
}

// ---------------- convert f32 -> bf16 (straight) ----------------
__global__ __launch_bounds__(256) void cvt_bf16_kernel(const float* __restrict__ in,
                                                       __bf16* __restrict__ out, int n4) {
  int i = blockIdx.x * 256 + threadIdx.x;
  if (i < n4) {
    float4 v = ((const float4*)in)[i];
    union { __bf16 b[4]; uint2 u; } t;
    t.b[0] = (__bf16)v.x; t.b[1] = (__bf16)v.y;
    t.b[2] = (__bf16)v.z; t.b[3] = (__bf16)v.w;
    ((uint2*)out)[i] = t.u;
  }
}

// ---------------- transpose-convert both weights in one launch ----------------
__global__ __launch_bounds__(256) void transpose_w_kernel(const float* __restrict__ Wq,
                                                          __bf16* __restrict__ WqT,
                                                          const float* __restrict__ Wo,
                                                          __bf16* __restrict__ WoT) {
  const int Kd = 1024;
  int bx = blockIdx.x;
  const float* W; __bf16* WT; int Nd, n0;
  if (bx < 96) { W = Wq; WT = WqT; Nd = 3072; n0 = bx * 32; }
  else         { W = Wo; WT = WoT; Nd = 1024; n0 = (bx - 96) * 32; }
  __shared__ float tile[32][33];
  int k0 = blockIdx.y * 32;
  int tid = threadIdx.x;
  int kk = tid >> 3, nn = (tid & 7) * 4;
  float4 v = *(const float4*)&W[(size_t)(k0 + kk) * Nd + n0 + nn];
  tile[kk][nn] = v.x; tile[kk][nn + 1] = v.y;
  tile[kk][nn + 2] = v.z; tile[kk][nn + 3] = v.w;
  __syncthreads();
  int n2 = tid >> 3, k2 = (tid & 7) * 4;
  union { __bf16 b[4]; uint2 u; } t;
  t.b[0] = (__bf16)tile[k2][n2];
  t.b[1] = (__bf16)tile[k2 + 1][n2];
  t.b[2] = (__bf16)tile[k2 + 2][n2];
  t.b[3] = (__bf16)tile[k2 + 3][n2];
  *(uint2*)&WT[(size_t)(n0 + n2) * Kd + k0 + k2] = t.u;
}

// ---------------- GEMM: C[M,N] = A[M,1024] @ BT[N,1024]^T + bias ----------------
template <bool OUT_F32, int NT>
__global__ __launch_bounds__(256) void gemm_kernel(const __bf16* __restrict__ A,
                                                   const __bf16* __restrict__ BT,
                                                   const float* __restrict__ bias,
                                                   void* __restrict__ Cout, int N,
                                                   int qn, float qs) {
  const int K = 1024;
  const int NJ = NT / 32;
  __shared__ __align__(16) __bf16 As[2][128 * 32];
  __shared__ __align__(16) __bf16 Bs[2][NT * 32];
  int tid = threadIdx.x;
  int wave = tid >> 6, lane = tid & 63;
  int quad = lane >> 4, l16 = lane & 15;
  int m0 = blockIdx.x * 128, n0 = blockIdx.y * NT;
  int wm = (wave >> 1) * 64, wn = (wave & 1) * (NT / 2);

  int srow = tid >> 2, scol = (tid & 3) * 8;
  const __bf16* aptr = A + (size_t)(m0 + srow) * K + scol;
  const __bf16* bptr = BT + (size_t)(n0 + srow) * K + scol;

  f32x4 acc[4][NJ] = {};
  for (int k0 = 0; k0 < K; k0 += 64) {
#pragma unroll
    for (int kh = 0; kh < 2; kh++) {
      GLDS16(aptr + k0 + kh * 32, &As[kh][wave * 512]);
      GLDS16(aptr + (size_t)64 * K + k0 + kh * 32, &As[kh][wave * 512 + 2048]);
      GLDS16(bptr + k0 + kh * 32, &Bs[kh][wave * 512]);
      if (NT == 128) GLDS16(bptr + (size_t)64 * K + k0 + kh * 32, &Bs[kh][wave * 512 + 2048]);
    }
    __syncthreads();
#pragma unroll
    for (int kh = 0; kh < 2; kh++) {
      bf16x8 af[4], bf[NJ];
      for (int i = 0; i < 4; i++)
        af[i] = *(bf16x8*)&As[kh][(wm + i * 16 + l16) * 32 + quad * 8];
      for (int j = 0; j < NJ; j++)
        bf[j] = *(bf16x8*)&Bs[kh][(wn + j * 16 + l16) * 32 + quad * 8];
      for (int i = 0; i < 4; i++)
        for (int j = 0; j < NJ; j++)
          acc[i][j] = MFMA16(af[i], bf[j], acc[i][j]);
    }
    __syncthreads();
  }
  for (int j = 0; j < NJ; j++) {
    int col = n0 + wn + j * 16 + l16;
    float bv = bias[col];
    float sc = (col < qn) ? qs : 1.0f;
    for (int i = 0; i < 4; i++) {
      int rowb = m0 + wm + i * 16 + quad * 4;
      for (int r = 0; r < 4; r++) {
        float v = (acc[i][j][r] + bv) * sc;
        if (OUT_F32)
          ((float*)Cout)[(size_t)(rowb + r) * N + col] = v;
        else
          ((__bf16*)Cout)[(size_t)(rowb + r) * N + col] = (__bf16)v;
      }
    }
  }
}

// ---------------- transpose V slice of qkv -> Vt [b][h][d][t] ----------------
__global__ __launch_bounds__(256) void transpose_v_kernel(const __bf16* __restrict__ qkv,
                                                          __bf16* __restrict__ Vt) {
  const int T = 2048, C3 = 3072;
  __shared__ __align__(16) __bf16 tile[64][72];
  int t0 = blockIdx.x * 64;
  int h = blockIdx.y, b = blockIdx.z;
  int tid = threadIdx.x;
  int tt = tid >> 2, c = (tid & 3) * 16;
  const __bf16* src = qkv + (size_t)(b * T + t0 + tt) * C3 + 2048 + h * 64 + c;
  *(uint4*)&tile[tt][c] = *(const uint4*)src;
  *(uint4*)&tile[tt][c + 8] = *(const uint4*)(src + 8);
  __syncthreads();
  int dd = tid >> 2, t2 = (tid & 3) * 16;
  union { __bf16 b_[16]; uint4 u[2]; } o;
  for (int i = 0; i < 16; i++) o.b_[i] = tile[t2 + i][dd];
  __bf16* dst = Vt + ((size_t)(b * 16 + h) * 64 + dd) * T + t0 + t2;
  *(uint4*)dst = o.u[0];
  *(uint4*)(dst + 8) = o.u[1];
}

// ---------------- flash attention v7: 32x32 MFMA + split-KV + private tiles ----
// grid 2048 x 256 thr. Block owns 32 q-rows of one (b,h); its 4 waves each own a
// T/4=512 KV range with a PRIVATE single-buffered 8 KB K/V LDS tile (32 kv),
// staged via coalesced swizzled GLDS. No barriers in the loop: per-wave
// s_waitcnt vmcnt(0) after staging; per-wave DS ordering covers the rest.
// S^T = K.Q^T (q in lane) -> P packed b64 into stride-36 region aliasing the
// dead K tile; row sums are free f32 adds. Partial O/ls combined via LDS once.
// XCD locality: bh = bid&31 so all q-blocks of one (b,h) share bid%8.
__global__ __launch_bounds__(256) void attn_kernel(const __bf16* __restrict__ qkv,
                                                   const __bf16* __restrict__ Vt,
                                                   __bf16* __restrict__ O) {
  const int T = 2048, C3 = 3072;
  int bid = blockIdx.x;
  int bh = bid & 31;
  int q0 = (bid >> 5) * 32;
  int b = bh >> 4, h = bh & 15;
  int tid = threadIdx.x, wave = tid >> 6, lane = tid & 63;
  int l31 = lane & 31, hw = lane >> 5;

  __shared__ __align__(16) __bf16 sm[16384];  // 32 KB total
  __bf16* Kbuf = sm + wave * 4096;            // 32x64 row-major, row&7 XOR swizzle
  __bf16* Vbuf = Kbuf + 2048;                 // 64x32 row-major, (r^(r>>2))&3 swizzle

  // Q B-frags: lane n=q=l31, k=d chunks (c*16 + hw*8 + j)
  const __bf16* qp = qkv + (size_t)(b * T + q0 + l31) * C3 + h * 64 + hw * 8;
  bf16x8 bq[4];
#pragma unroll
  for (int c = 0; c < 4; c++) bq[c] = *(const bf16x8*)(qp + c * 16);

  const __bf16* kbase = qkv + (size_t)(b * T) * C3 + 1024 + h * 64;
  const __bf16* vtb = Vt + (size_t)bh * 64 * T;

  // staging lane decode (coalesced: K 8 lanes/row of 128B, V 4 lanes/row of 64B)
  int srK = lane >> 3, scK = ((lane & 7) ^ srK) * 8;
  int srV = lane >> 2;
  int scV = ((lane & 3) ^ ((srV ^ (srV >> 2)) & 3)) * 8;
  int vsw = (l31 ^ (l31 >> 2)) & 3;

  int tw0 = wave * 512;  // this wave's KV quarter

#define STAGE(tt)                                                        \
  {                                                                      \
    _Pragma("unroll") for (int i = 0; i < 4; i++)                        \
        GLDS16(kbase + (size_t)((tt) + i * 8 + srK) * C3 + scK,          \
               Kbuf + i * 512);                                          \
    _Pragma("unroll") for (int i = 0; i < 4; i++)                        \
        GLDS16(vtb + (size_t)(i * 16 + srV) * T + (tt) + scV,            \
               Vbuf + i * 512);                                          \
  }

  f32x16 o0 = {}, o1 = {};
  float lsa = 0.f;

  STAGE(tw0);
  for (int it = 0; it < 16; it++) {
    __builtin_amdgcn_s_waitcnt(0);  // staged tile landed in LDS

    // S^T = K Q^T : lane holds col q=l31, rows t (16 regs)
    f32x16 ss = {};
#pragma unroll
    for (int c = 0; c < 4; c++) {
      bf16x8 kf = *(const bf16x8*)&Kbuf[l31 * 64 + (((c * 2 + hw) ^ (l31 & 7)) * 8)];
      ss = MFMA32(kf, bq[c], ss);
    }

    // P = exp2(S^T), packed b64 into P region (aliases dead K tile), stride 36
#pragma unroll
    for (int g = 0; g < 4; g++) {
      float e0 = __builtin_amdgcn_exp2f(ss[4 * g]);
      float e1 = __builtin_amdgcn_exp2f(ss[4 * g + 1]);
      float e2 = __builtin_amdgcn_exp2f(ss[4 * g + 2]);
      float e3 = __builtin_amdgcn_exp2f(ss[4 * g + 3]);
      lsa += (e0 + e1) + (e2 + e3);
      uint2 pw;
      pw.x = pack_bf16(e0, e1);
      pw.y = pack_bf16(e2, e3);
      *(uint2*)&Kbuf[l31 * 36 + g * 8 + hw * 4] = pw;  // t = 8g+4hw+(0..3), q = l31
    }

    // O += P V : A = P[m=q][k=t], B = V[k=t][n=d]
#pragma unroll
    for (int ks = 0; ks < 2; ks++) {
      bf16x8 ap = *(const bf16x8*)&Kbuf[l31 * 36 + ks * 16 + hw * 8];
      int xb = ((ks * 2 + hw) ^ vsw) * 8;
      bf16x8 bv0 = *(const bf16x8*)&Vbuf[l31 * 32 + xb];
      bf16x8 bv1 = *(const bf16x8*)&Vbuf[(32 + l31) * 32 + xb];
      o0 = MFMA32(ap, bv0, o0);
      o1 = MFMA32(ap, bv1, o1);
    }

    if (it < 15) STAGE(tw0 + (it + 1) * 32);
  }
#undef STAGE

  // cross-half row-sum combine (halves hold complementary t's for same q=l31)
  int lsp = __builtin_amdgcn_ds_bpermute((lane ^ 32) << 2,
                                         __builtin_bit_cast(int, lsa));
  float lst = lsa + __builtin_bit_cast(float, lsp);

  // block combine: waves 1..3 dump partials, wave 0 sums + writes
  __syncthreads();
  float* cm = (float*)sm;
  if (wave > 0) {
    float* pw = cm + (wave - 1) * 2176 + lane * 34;  // 136B stride: 8B-aligned, 2-way
#pragma unroll
    for (int i = 0; i < 8; i++) {
      f32x2 v0; v0.x = o0[2 * i]; v0.y = o0[2 * i + 1];
      *(f32x2*)(pw + 2 * i) = v0;
      f32x2 v1; v1.x = o1[2 * i]; v1.y = o1[2 * i + 1];
      *(f32x2*)(pw + 16 + 2 * i) = v1;
    }
    cm[6528 + (wave - 1) * 64 + lane] = lst;
  }
  __syncthreads();
  if (wave == 0) {
#pragma unroll
    for (int w = 0; w < 3; w++) {
      float* pr = cm + w * 2176 + lane * 34;
#pragma unroll
      for (int i = 0; i < 8; i++) {
        f32x2 v0 = *(f32x2*)(pr + 2 * i);
        o0[2 * i] += v0.x; o0[2 * i + 1] += v0.y;
        f32x2 v1 = *(f32x2*)(pr + 16 + 2 * i);
        o1[2 * i] += v1.x; o1[2 * i + 1] += v1.y;
      }
      lst += cm[6528 + w * 64 + lane];
    }
    // epilogue: col = d (o0: l31, o1: 32+l31), row = q = (reg&3)+8*(reg>>2)+4*hw
    __bf16* obase = O + (size_t)(b * T + q0) * 1024 + h * 64 + l31;
#pragma unroll
    for (int reg = 0; reg < 16; reg++) {
      int q = (reg & 3) + 8 * (reg >> 2) + 4 * hw;
      float lq = __shfl(lst, q, 64);  // row-q sum lives in lane l31==q
      float inv = 1.0f / lq;
      obase[(size_t)q * 1024] = (__bf16)(o0[reg] * inv);
      obase[(size_t)q * 1024 + 32] = (__bf16)(o1[reg] * inv);
    }
  }
}

// ---------------- launch ----------------
extern "C" void kernel_launch(void* const* d_in, const int* in_sizes, int n_in,
                              void* d_out, int out_size, void* d_ws, size_t ws_size,
                              hipStream_t stream) {
  const float* x = (const float*)d_in[0];      // [2,2048,1024]
  const float* W_qkv = (const float*)d_in[1];  // [1024,3072]
  const float* b_qkv = (const float*)d_in[2];  // [3072]
  const float* W_out = (const float*)d_in[3];  // [1024,1024]
  const float* b_out = (const float*)d_in[4];  // [1024]
  float* out = (float*)d_out;                  // [2,2048,1024] f32

  char* ws = (char*)d_ws;
  __bf16* WqkvT = (__bf16*)(ws);               // [3072][1024]  6 MB
  __bf16* WoT = (__bf16*)(ws + 6291456);       // [1024][1024]  2 MB
  __bf16* xb = (__bf16*)(ws + 8388608);        // [4096][1024]  8 MB
  __bf16* qkvb = (__bf16*)(ws + 16777216);     // [4096][3072] 24 MB
  __bf16* Vt = (__bf16*)(ws + 41943040);       // [2][16][64][2048] 8 MB
  __bf16* attnb = xb;  // xb dead after gemm1; reuse for attention output

  const float cs = 0.125f * 1.44269504089f;  // 1/sqrt(64) * log2(e)

  cvt_bf16_kernel<<<4096, 256, 0, stream>>>(x, xb, 1048576);
  transpose_w_kernel<<<dim3(128, 32), 256, 0, stream>>>(W_qkv, WqkvT, W_out, WoT);
  gemm_kernel<false, 128><<<dim3(32, 24), 256, 0, stream>>>(xb, WqkvT, b_qkv, qkvb, 3072,
                                                            1024, cs);
  transpose_v_kernel<<<dim3(32, 16, 2), 256, 0, stream>>>(qkvb, Vt);
  attn_kernel<<<2048, 256, 0, stream>>>(qkvb, Vt, attnb);
  gemm_kernel<true, 64><<<dim3(32, 16), 256, 0, stream>>>(attnb, WoT, b_out, out, 1024,
                                                          0, 1.0f);
}